// Round 2
// baseline (623.240 us; speedup 1.0000x reference)
//
#include <hip/hip_runtime.h>

// Equivariant linear: irreps [(32,1),(16,3),(8,5),(4,7)], DIM=148.
// out[n, off + v*d + i] = mul^-0.5 * sum_u x[n, off + u*d + i] * w[u*mul + v]
//
// R2: 16 rows per wave (9.25 KB LDS), 4 waves/WG, per-wave decoupled phases
// (s_waitcnt vmcnt(0), no __syncthreads) -> 16 waves/CU = 4 waves/SIMD.
// 4 lanes per row split by output-multiplicity chunk; weights via L1-hot
// per-lane vector loads.

#define ROWF   148               // floats per row
#define ROWF4  37                // float4 per row
#define RPW    16                // rows per wave
#define WPB    4                 // waves per block
#define ROWS_WG (RPW * WPB)      // 64 rows per WG
#define WAVE_F4 (RPW * ROWF4)    // 592 float4 per wave tile (= 9*64 + 16)

typedef const __attribute__((address_space(1))) void* gptr_t;
typedef __attribute__((address_space(3))) void* lptr_t;

__global__ __launch_bounds__(256, 4) void eqlin_kernel(
    const float* __restrict__ x,
    const float* __restrict__ w0,
    const float* __restrict__ w1,
    const float* __restrict__ w2,
    const float* __restrict__ w3,
    float* __restrict__ out) {
    __shared__ float lds[WPB * RPW * ROWF];  // 37888 B -> 4 WG/CU

    const int tid  = threadIdx.x;
    const int wave = tid >> 6;
    const int lane = tid & 63;
    float* xseg = lds + wave * (RPW * ROWF);
    const size_t base_f4 = ((size_t)blockIdx.x * ROWS_WG + wave * RPW) * ROWF4;

    // ---- Stage: global -> LDS (per-wave, coalesced, width-16 DMA) ----
    {
        const float4* src = (const float4*)x + base_f4 + lane;
#pragma unroll
        for (int j = 0; j < 9; ++j) {
            __builtin_amdgcn_global_load_lds(
                (gptr_t)(src + j * 64),
                (lptr_t)(xseg + j * 256 + lane * 4), 16, 0, 0);
        }
        if (lane < 16) {
            __builtin_amdgcn_global_load_lds(
                (gptr_t)(src + 9 * 64),
                (lptr_t)(xseg + 9 * 256 + lane * 4), 16, 0, 0);
        }
    }
    __builtin_amdgcn_s_waitcnt(0x0F70);  // vmcnt(0) only — per-wave drain

    // ---- Compute: 4 lanes per row, lane q owns an output-v chunk ----
    const int r = lane >> 2;
    const int q = lane & 3;
    float* row = xseg + r * ROWF;

    // block 0: 32x0e, lane computes v in [8q, 8q+8)
    {
        float xv[32];
#pragma unroll
        for (int j = 0; j < 8; ++j) {
            float4 v = ((const float4*)row)[j];
            xv[4 * j] = v.x; xv[4 * j + 1] = v.y;
            xv[4 * j + 2] = v.z; xv[4 * j + 3] = v.w;
        }
        float acc[8];
#pragma unroll
        for (int k = 0; k < 8; ++k) acc[k] = 0.0f;
        const float* wq = w0 + 8 * q;
#pragma unroll
        for (int u = 0; u < 32; ++u) {
            float4 wa = *(const float4*)(wq + u * 32);
            float4 wb = *(const float4*)(wq + u * 32 + 4);
            acc[0] += xv[u] * wa.x; acc[1] += xv[u] * wa.y;
            acc[2] += xv[u] * wa.z; acc[3] += xv[u] * wa.w;
            acc[4] += xv[u] * wb.x; acc[5] += xv[u] * wb.y;
            acc[6] += xv[u] * wb.z; acc[7] += xv[u] * wb.w;
        }
        const float s = 0.17677669529663687f;  // 32^-0.5
        float4* op = (float4*)(row + 8 * q);
        float4 o0, o1;
        o0.x = acc[0] * s; o0.y = acc[1] * s; o0.z = acc[2] * s; o0.w = acc[3] * s;
        o1.x = acc[4] * s; o1.y = acc[5] * s; o1.z = acc[6] * s; o1.w = acc[7] * s;
        op[0] = o0; op[1] = o1;
    }

    // block 1: 16x1o, lane computes v in [4q, 4q+4)  (12 contiguous floats)
    {
        float xv[48];
#pragma unroll
        for (int j = 0; j < 12; ++j) {
            float4 v = ((const float4*)(row + 32))[j];
            xv[4 * j] = v.x; xv[4 * j + 1] = v.y;
            xv[4 * j + 2] = v.z; xv[4 * j + 3] = v.w;
        }
        float acc[12];
#pragma unroll
        for (int k = 0; k < 12; ++k) acc[k] = 0.0f;
        const float* wq = w1 + 4 * q;
#pragma unroll
        for (int u = 0; u < 16; ++u) {
            float4 wv = *(const float4*)(wq + u * 16);
            const float x0 = xv[u * 3], x1 = xv[u * 3 + 1], x2 = xv[u * 3 + 2];
            acc[0] += x0 * wv.x; acc[1]  += x1 * wv.x; acc[2]  += x2 * wv.x;
            acc[3] += x0 * wv.y; acc[4]  += x1 * wv.y; acc[5]  += x2 * wv.y;
            acc[6] += x0 * wv.z; acc[7]  += x1 * wv.z; acc[8]  += x2 * wv.z;
            acc[9] += x0 * wv.w; acc[10] += x1 * wv.w; acc[11] += x2 * wv.w;
        }
        const float s = 0.25f;  // 16^-0.5
        float4* op = (float4*)(row + 32 + 12 * q);
#pragma unroll
        for (int j = 0; j < 3; ++j) {
            float4 o;
            o.x = acc[4 * j] * s;     o.y = acc[4 * j + 1] * s;
            o.z = acc[4 * j + 2] * s; o.w = acc[4 * j + 3] * s;
            op[j] = o;
        }
    }

    // block 2: 8x2e, lane computes v in [2q, 2q+2)  (10 contiguous floats)
    {
        float xv[40];
#pragma unroll
        for (int j = 0; j < 10; ++j) {
            float4 v = ((const float4*)(row + 80))[j];
            xv[4 * j] = v.x; xv[4 * j + 1] = v.y;
            xv[4 * j + 2] = v.z; xv[4 * j + 3] = v.w;
        }
        float acc[10];
#pragma unroll
        for (int k = 0; k < 10; ++k) acc[k] = 0.0f;
        const float* wq = w2 + 2 * q;
#pragma unroll
        for (int u = 0; u < 8; ++u) {
            float2 wv = *(const float2*)(wq + u * 8);
#pragma unroll
            for (int i = 0; i < 5; ++i) {
                acc[i]     += xv[u * 5 + i] * wv.x;
                acc[5 + i] += xv[u * 5 + i] * wv.y;
            }
        }
        const float s = 0.35355339059327373f;  // 8^-0.5
        float2* op = (float2*)(row + 80 + 10 * q);
#pragma unroll
        for (int j = 0; j < 5; ++j) {
            float2 o;
            o.x = acc[2 * j] * s; o.y = acc[2 * j + 1] * s;
            op[j] = o;
        }
    }

    // block 3: 4x3o, lane computes v = q  (7 contiguous floats)
    {
        float xv[28];
#pragma unroll
        for (int j = 0; j < 7; ++j) {
            float4 v = ((const float4*)(row + 120))[j];
            xv[4 * j] = v.x; xv[4 * j + 1] = v.y;
            xv[4 * j + 2] = v.z; xv[4 * j + 3] = v.w;
        }
        float acc[7];
#pragma unroll
        for (int k = 0; k < 7; ++k) acc[k] = 0.0f;
        const float* wq = w3 + q;
#pragma unroll
        for (int u = 0; u < 4; ++u) {
            float wv = wq[u * 4];
#pragma unroll
            for (int i = 0; i < 7; ++i) acc[i] += xv[u * 7 + i] * wv;
        }
        const float s = 0.5f;  // 4^-0.5
        float* op = row + 120 + 7 * q;
#pragma unroll
        for (int i = 0; i < 7; ++i) op[i] = acc[i] * s;
    }

    // ---- Flush: LDS -> global (per-wave, coalesced) ----
    // DS ops are in-order per wave; all producers are this wave's lanes.
    {
        const float4* lseg4 = (const float4*)xseg;
        float4* dst = (float4*)out + base_f4 + lane;
#pragma unroll
        for (int j = 0; j < 9; ++j) {
            dst[j * 64] = lseg4[j * 64 + lane];
        }
        if (lane < 16) {
            dst[9 * 64] = lseg4[9 * 64 + lane];
        }
    }
}

extern "C" void kernel_launch(void* const* d_in, const int* in_sizes, int n_in,
                              void* d_out, int out_size, void* d_ws, size_t ws_size,
                              hipStream_t stream) {
    const float* x  = (const float*)d_in[0];
    const float* w0 = (const float*)d_in[1];
    const float* w1 = (const float*)d_in[2];
    const float* w2 = (const float*)d_in[3];
    const float* w3 = (const float*)d_in[4];
    float* out = (float*)d_out;

    const int N = in_sizes[0] / ROWF;   // 524288
    const int tiles = N / ROWS_WG;      // 8192 (exact)

    eqlin_kernel<<<dim3(tiles), dim3(256), 0, stream>>>(x, w0, w1, w2, w3, out);
}